// Round 1
// baseline (431.324 us; speedup 1.0000x reference)
//
#include <hip/hip_runtime.h>
#include <hip/hip_bf16.h>
#include <math.h>

#define B_DIM 8
#define S_DIM 4096
#define DIN   1024
#define DHID  1024
#define DOUT  1024
#define KCAT  1040          // d_in + pe
#define KC    1056          // padded to %32==0
#define MTOT  (B_DIM*S_DIM) // 32768
#define NCHUNK 32
#define LCHUNK 128

typedef __attribute__((ext_vector_type(8))) short bf16x8;
typedef __attribute__((ext_vector_type(4))) float f32x4;
typedef __attribute__((ext_vector_type(4))) unsigned short u16x4;

__device__ __forceinline__ unsigned short f2bf(float f) {
  union { float f; unsigned u; } v; v.f = f;
  unsigned r = v.u + 0x7fffu + ((v.u >> 16) & 1u);
  return (unsigned short)(r >> 16);
}
__device__ __forceinline__ float bf2f(unsigned short h) {
  union { unsigned u; float f; } v; v.u = ((unsigned)h) << 16;
  return v.f;
}

// async global->LDS, 16B per lane; LDS dest = wave-uniform base + lane*16
#define GLOAD16(g, l)                                                         \
  __builtin_amdgcn_global_load_lds(                                           \
      (const __attribute__((address_space(1))) void*)(g),                     \
      (__attribute__((address_space(3))) void*)(l), 16, 0, 0)

// ---------------- prep kernels ----------------

__global__ void prep_a_kernel(const float* __restrict__ logit,
                              float* __restrict__ avec, float* __restrict__ svec) {
  int d = blockIdx.x * 256 + threadIdx.x;
  if (d >= DHID) return;
  float a = 1.f / (1.f + expf(-logit[d]));
  avec[d] = a;
  svec[d] = sqrtf(fmaxf(0.f, 1.f - a * a));
}

// W[K][N] fp32 -> Wt[N][KCdst] bf16 (zero-pad k >= Ksrc)
__global__ __launch_bounds__(256) void transpose_cast_kernel(
    const float* __restrict__ W, unsigned short* __restrict__ Wt,
    int Ksrc, int KCdst) {
  __shared__ float tile[32][33];
  const int N = 1024;
  int kb = blockIdx.x * 32, nb = blockIdx.y * 32;
  int tx = threadIdx.x & 31, ty = threadIdx.x >> 5;  // ty 0..7
#pragma unroll
  for (int r = 0; r < 32; r += 8) {
    int k = kb + ty + r;
    tile[ty + r][tx] = (k < Ksrc) ? W[(size_t)k * N + nb + tx] : 0.f;
  }
  __syncthreads();
#pragma unroll
  for (int r = 0; r < 32; r += 8) {
    int n = nb + ty + r;
    Wt[(size_t)n * KCdst + kb + tx] = f2bf(tile[tx][ty + r]);
  }
}

// xc[row][0..1023]=x, [1024..1039]=PE(t), [1040..1055]=0   (bf16)
__global__ __launch_bounds__(256) void build_xc_kernel(
    const float* __restrict__ x, unsigned short* __restrict__ xc) {
  int gid = blockIdx.x * 256 + threadIdx.x;  // over MTOT * (KC/4)
  if (gid >= MTOT * (KC / 4)) return;
  int row = gid / (KC / 4);
  int g = gid - row * (KC / 4);
  int col0 = g * 4;
  u16x4 val;
  if (col0 < DIN) {
    const float4 xv = *(const float4*)(x + (size_t)row * DIN + col0);
    val.x = f2bf(xv.x); val.y = f2bf(xv.y); val.z = f2bf(xv.z); val.w = f2bf(xv.w);
  } else {
    int t = row & (S_DIM - 1);
#pragma unroll
    for (int e = 0; e < 4; e++) {
      int col = col0 + e;
      float v = 0.f;
      if (col < KCAT) {
        int j = col - DIN;
        int i = j >> 1;
        float div = expf(-(float)i * 1.1512925465f);  // 10000^(-i/8)
        float arg = (float)t * div;
        v = (j & 1) ? cosf(arg) : sinf(arg);
      }
      val[e] = f2bf(v);
    }
  }
  *(u16x4*)(xc + (size_t)row * KC + col0) = val;
}

// ---------------- GEMM (128x128 tile, 4 waves, 16x16x32 bf16 MFMA) ----------------

__device__ __forceinline__ void gemm_tile_loop(
    const unsigned short* __restrict__ A,   // [M][lda] bf16, row-major
    const unsigned short* __restrict__ Bt,  // [N][lda] bf16, row-major (B transposed)
    int lda, int ksteps, int brow, int bcol,
    unsigned short* As, unsigned short* Bs, f32x4 acc[4][4]) {
  const int tid = threadIdx.x;
  const int wid = tid >> 6;
  const int lane = tid & 63;
  const int wrow = wid >> 1, wcol = wid & 1;

  // staging: seg = wid*2 + call covers 16 rows of the tile
  const int srow = (lane >> 2);           // 0..15 within seg
  const int skoff = (lane & 3) * 8;       // element offset in K-slice
  const unsigned short* ga_base = A + (size_t)(brow * 128 + wid * 32 + srow) * lda + skoff;
  const unsigned short* gb_base = Bt + (size_t)(bcol * 128 + wid * 32 + srow) * lda + skoff;
  unsigned short* AsB = As + wid * 32 * 32;  // wave-uniform LDS base (elements)
  unsigned short* BsB = Bs + wid * 32 * 32;
  const size_t row16 = (size_t)16 * lda;

  for (int ks = 0; ks < ksteps; ++ks) {
    const size_t k0 = (size_t)ks * 32;
    GLOAD16(ga_base + k0, AsB);
    GLOAD16(ga_base + k0 + row16, AsB + 16 * 32);
    GLOAD16(gb_base + k0, BsB);
    GLOAD16(gb_base + k0 + row16, BsB + 16 * 32);
    __syncthreads();

    bf16x8 af[4], bfr[4];
#pragma unroll
    for (int m = 0; m < 4; m++)
      af[m] = *(const bf16x8*)&As[(wrow * 64 + m * 16 + (lane & 15)) * 32 + (lane >> 4) * 8];
#pragma unroll
    for (int n = 0; n < 4; n++)
      bfr[n] = *(const bf16x8*)&Bs[(wcol * 64 + n * 16 + (lane & 15)) * 32 + (lane >> 4) * 8];
#pragma unroll
    for (int m = 0; m < 4; m++)
#pragma unroll
      for (int n = 0; n < 4; n++)
        acc[m][n] = __builtin_amdgcn_mfma_f32_16x16x32_bf16(af[m], bfr[n], acc[m][n], 0, 0, 0);
    __syncthreads();
  }
}

// u = bf16( svec[col] * (xc @ W_in + b_in) )
__global__ __launch_bounds__(256) void gemm_u_kernel(
    const unsigned short* __restrict__ xc, const unsigned short* __restrict__ Wtin,
    const float* __restrict__ b_in, const float* __restrict__ svec,
    unsigned short* __restrict__ u) {
  __shared__ __align__(16) unsigned short As[128 * 32];
  __shared__ __align__(16) unsigned short Bs[128 * 32];
  f32x4 acc[4][4];
  const f32x4 z = {0.f, 0.f, 0.f, 0.f};
#pragma unroll
  for (int m = 0; m < 4; m++)
#pragma unroll
    for (int n = 0; n < 4; n++) acc[m][n] = z;

  const int bcol = blockIdx.x, brow = blockIdx.y;
  gemm_tile_loop(xc, Wtin, KC, KC / 32, brow, bcol, As, Bs, acc);

  const int lane = threadIdx.x & 63, wid = threadIdx.x >> 6;
  const int wrow = wid >> 1, wcol = wid & 1;
  const int colb = bcol * 128 + wcol * 64 + (lane & 15);
  const int rowb = brow * 128 + wrow * 64 + (lane >> 4) * 4;
#pragma unroll
  for (int n = 0; n < 4; n++) {
    int col = colb + n * 16;
    float bi = b_in[col], sv = svec[col];
#pragma unroll
    for (int m = 0; m < 4; m++) {
#pragma unroll
      for (int r = 0; r < 4; r++) {
        int row = rowb + m * 16 + r;
        u[(size_t)row * DHID + col] = f2bf((acc[m][n][r] + bi) * sv);
      }
    }
  }
}

// out = 0.5f * (xc @ W_dx + h @ W_out + b_dx + b_out)
__global__ __launch_bounds__(256) void gemm_out_kernel(
    const unsigned short* __restrict__ xc, const unsigned short* __restrict__ Wtdx,
    const unsigned short* __restrict__ h, const unsigned short* __restrict__ Wtout,
    const float* __restrict__ b_dx, const float* __restrict__ b_out,
    float* __restrict__ out) {
  __shared__ __align__(16) unsigned short As[128 * 32];
  __shared__ __align__(16) unsigned short Bs[128 * 32];
  f32x4 acc[4][4];
  const f32x4 z = {0.f, 0.f, 0.f, 0.f};
#pragma unroll
  for (int m = 0; m < 4; m++)
#pragma unroll
    for (int n = 0; n < 4; n++) acc[m][n] = z;

  const int bcol = blockIdx.x, brow = blockIdx.y;
  gemm_tile_loop(xc, Wtdx, KC, KC / 32, brow, bcol, As, Bs, acc);
  gemm_tile_loop(h, Wtout, DHID, DHID / 32, brow, bcol, As, Bs, acc);

  const int lane = threadIdx.x & 63, wid = threadIdx.x >> 6;
  const int wrow = wid >> 1, wcol = wid & 1;
  const int colb = bcol * 128 + wcol * 64 + (lane & 15);
  const int rowb = brow * 128 + wrow * 64 + (lane >> 4) * 4;
#pragma unroll
  for (int n = 0; n < 4; n++) {
    int col = colb + n * 16;
    float bb = b_dx[col] + b_out[col];
#pragma unroll
    for (int m = 0; m < 4; m++) {
#pragma unroll
      for (int r = 0; r < 4; r++) {
        int row = rowb + m * 16 + r;
        out[(size_t)row * DOUT + col] = 0.5f * (acc[m][n][r] + bb);
      }
    }
  }
}

// ---------------- chunked scan: h_t = a h_{t-1} + u_t ----------------

// pass 1: local scan per chunk (in place u->h_local, bf16), emit chunk-final carry
__global__ __launch_bounds__(256) void scan1_kernel(
    const float* __restrict__ avec, unsigned short* __restrict__ uh,
    float* __restrict__ carry) {
  int blk = blockIdx.x;            // b(8) x c(32) x dblk(4)
  int d = (blk & 3) * 256 + threadIdx.x;
  int c = (blk >> 2) & 31;
  int b = blk >> 7;
  float a = avec[d];
  unsigned short* p = uh + ((size_t)(b * S_DIM + c * LCHUNK)) * DHID + d;
  float h = 0.f;
#pragma unroll 4
  for (int t = 0; t < LCHUNK; t++) {
    float uv = bf2f(p[(size_t)t * DHID]);
    h = fmaf(a, h, uv);
    p[(size_t)t * DHID] = f2bf(h);
  }
  carry[((size_t)b * NCHUNK + c) * DHID + d] = h;
}

// pass 2: sequential combine over chunks (8192 threads)
__global__ __launch_bounds__(256) void scan2_kernel(
    const float* __restrict__ avec, const float* __restrict__ carry,
    float* __restrict__ Hprev) {
  int gid = blockIdx.x * 256 + threadIdx.x;  // 0..8191
  int b = gid >> 10, d = gid & 1023;
  float a = avec[d];
  float aL = a;
#pragma unroll
  for (int i = 0; i < 7; i++) aL *= aL;  // a^128
  float H = 0.f;
#pragma unroll
  for (int c = 0; c < NCHUNK; c++) {
    size_t idx = ((size_t)b * NCHUNK + c) * DHID + d;
    Hprev[idx] = H;
    H = aL * H + carry[idx];
  }
}

// pass 3: h_t += a^{t+1} * Hprev[chunk]
__global__ __launch_bounds__(256) void scan3_kernel(
    const float* __restrict__ avec, unsigned short* __restrict__ uh,
    const float* __restrict__ Hprev) {
  int blk = blockIdx.x;
  int d = (blk & 3) * 256 + threadIdx.x;
  int c = (blk >> 2) & 31;
  int b = blk >> 7;
  float Hp = Hprev[((size_t)b * NCHUNK + c) * DHID + d];
  if (Hp == 0.f) return;  // c==0 (and exact zeros): values unchanged
  float a = avec[d];
  float pw = a;
  unsigned short* p = uh + ((size_t)(b * S_DIM + c * LCHUNK)) * DHID + d;
#pragma unroll 4
  for (int t = 0; t < LCHUNK; t++) {
    float hv = bf2f(p[(size_t)t * DHID]) + pw * Hp;
    p[(size_t)t * DHID] = f2bf(hv);
    pw *= a;
  }
}

// ---------------- launch ----------------

extern "C" void kernel_launch(void* const* d_in, const int* in_sizes, int n_in,
                              void* d_out, int out_size, void* d_ws, size_t ws_size,
                              hipStream_t stream) {
  const float* x       = (const float*)d_in[0];
  const float* a_logit = (const float*)d_in[1];
  const float* W_dx    = (const float*)d_in[2];
  const float* b_dx    = (const float*)d_in[3];
  const float* W_in    = (const float*)d_in[4];
  const float* b_in    = (const float*)d_in[5];
  const float* W_out   = (const float*)d_in[6];
  const float* b_out   = (const float*)d_in[7];
  float* out = (float*)d_out;

  char* ws = (char*)d_ws;
  size_t off = 0;
  auto alloc = [&](size_t bytes) {
    void* p = ws + off;
    off += (bytes + 255) & ~(size_t)255;
    return p;
  };
  unsigned short* xc    = (unsigned short*)alloc((size_t)MTOT * KC * 2);
  unsigned short* Wtdx  = (unsigned short*)alloc((size_t)DOUT * KC * 2);
  unsigned short* Wtin  = (unsigned short*)alloc((size_t)DHID * KC * 2);
  unsigned short* Wtout = (unsigned short*)alloc((size_t)DOUT * DHID * 2);
  unsigned short* uh    = (unsigned short*)alloc((size_t)MTOT * DHID * 2);
  float* carry = (float*)alloc((size_t)B_DIM * NCHUNK * DHID * 4);
  float* Hprev = (float*)alloc((size_t)B_DIM * NCHUNK * DHID * 4);
  float* avec  = (float*)alloc(DHID * 4);
  float* svec  = (float*)alloc(DHID * 4);
  (void)ws_size; (void)in_sizes; (void)n_in; (void)out_size;

  prep_a_kernel<<<4, 256, 0, stream>>>(a_logit, avec, svec);
  transpose_cast_kernel<<<dim3(KC / 32, 32), 256, 0, stream>>>(W_dx, Wtdx, KCAT, KC);
  transpose_cast_kernel<<<dim3(KC / 32, 32), 256, 0, stream>>>(W_in, Wtin, KCAT, KC);
  transpose_cast_kernel<<<dim3(32, 32), 256, 0, stream>>>(W_out, Wtout, DHID, DHID);
  build_xc_kernel<<<(MTOT * (KC / 4) + 255) / 256, 256, 0, stream>>>(x, xc);

  gemm_u_kernel<<<dim3(8, 256), 256, 0, stream>>>(xc, Wtin, b_in, svec, uh);

  scan1_kernel<<<B_DIM * NCHUNK * 4, 256, 0, stream>>>(avec, uh, carry);
  scan2_kernel<<<32, 256, 0, stream>>>(avec, carry, Hprev);
  scan3_kernel<<<B_DIM * NCHUNK * 4, 256, 0, stream>>>(avec, uh, Hprev);

  gemm_out_kernel<<<dim3(8, 256), 256, 0, stream>>>(xc, Wtdx, uh, Wtout, b_dx, b_out, out);
}

// Round 2
// 415.717 us; speedup vs baseline: 1.0375x; 1.0375x over previous
//
#include <hip/hip_runtime.h>
#include <hip/hip_bf16.h>
#include <math.h>

#define B_DIM 8
#define S_DIM 4096
#define DIN   1024
#define DHID  1024
#define DOUT  1024
#define KCAT  1040          // d_in + pe
#define KC    1056          // padded to %32==0
#define MTOT  (B_DIM*S_DIM) // 32768
#define NCHUNK 32
#define LCHUNK 128

#define GBK 32              // K per tile

typedef __attribute__((ext_vector_type(8))) short bf16x8;
typedef __attribute__((ext_vector_type(4))) float f32x4;
typedef __attribute__((ext_vector_type(4))) unsigned short u16x4;

__device__ __forceinline__ unsigned short f2bf(float f) {
  union { float f; unsigned u; } v; v.f = f;
  unsigned r = v.u + 0x7fffu + ((v.u >> 16) & 1u);
  return (unsigned short)(r >> 16);
}
__device__ __forceinline__ float bf2f(unsigned short h) {
  union { unsigned u; float f; } v; v.u = ((unsigned)h) << 16;
  return v.f;
}

// async global->LDS, 16B per lane; LDS dest = wave-uniform base + lane*16
#define GLOAD16(g, l)                                                         \
  __builtin_amdgcn_global_load_lds(                                           \
      (const __attribute__((address_space(1))) void*)(g),                     \
      (__attribute__((address_space(3))) void*)(l), 16, 0, 0)

// ---------------- prep kernels ----------------

__global__ void prep_a_kernel(const float* __restrict__ logit,
                              float* __restrict__ avec, float* __restrict__ svec) {
  int d = blockIdx.x * 256 + threadIdx.x;
  if (d >= DHID) return;
  float a = 1.f / (1.f + expf(-logit[d]));
  avec[d] = a;
  svec[d] = sqrtf(fmaxf(0.f, 1.f - a * a));
}

// W[K][N] fp32 -> Wt[N][KCdst] bf16 (zero-pad k >= Ksrc)
__global__ __launch_bounds__(256) void transpose_cast_kernel(
    const float* __restrict__ W, unsigned short* __restrict__ Wt,
    int Ksrc, int KCdst) {
  __shared__ float tile[32][33];
  const int N = 1024;
  int kb = blockIdx.x * 32, nb = blockIdx.y * 32;
  int tx = threadIdx.x & 31, ty = threadIdx.x >> 5;  // ty 0..7
#pragma unroll
  for (int r = 0; r < 32; r += 8) {
    int k = kb + ty + r;
    tile[ty + r][tx] = (k < Ksrc) ? W[(size_t)k * N + nb + tx] : 0.f;
  }
  __syncthreads();
#pragma unroll
  for (int r = 0; r < 32; r += 8) {
    int n = nb + ty + r;
    Wt[(size_t)n * KCdst + kb + tx] = f2bf(tile[tx][ty + r]);
  }
}

// xc[row][0..1023]=x, [1024..1039]=PE(t), [1040..1055]=0   (bf16)
__global__ __launch_bounds__(256) void build_xc_kernel(
    const float* __restrict__ x, unsigned short* __restrict__ xc) {
  int gid = blockIdx.x * 256 + threadIdx.x;  // over MTOT * (KC/4)
  if (gid >= MTOT * (KC / 4)) return;
  int row = gid / (KC / 4);
  int g = gid - row * (KC / 4);
  int col0 = g * 4;
  u16x4 val;
  if (col0 < DIN) {
    const float4 xv = *(const float4*)(x + (size_t)row * DIN + col0);
    val.x = f2bf(xv.x); val.y = f2bf(xv.y); val.z = f2bf(xv.z); val.w = f2bf(xv.w);
  } else {
    int t = row & (S_DIM - 1);
#pragma unroll
    for (int e = 0; e < 4; e++) {
      int col = col0 + e;
      float v = 0.f;
      if (col < KCAT) {
        int j = col - DIN;
        int i = j >> 1;
        float div = expf(-(float)i * 1.1512925465f);  // 10000^(-i/8)
        float arg = (float)t * div;
        v = (j & 1) ? cosf(arg) : sinf(arg);
      }
      val[e] = f2bf(v);
    }
  }
  *(u16x4*)(xc + (size_t)row * KC + col0) = val;
}

// ------------- 256x256 deep-pipelined GEMM (4-buffer, counted vmcnt) -------------
// LDS per buffer: A/B tile [256 rows][32 K] bf16 = 16KB. Chunk = 16B (row<<2|slot).
// Swizzle: phys_slot = slot ^ ((row>>1)&3)  (involution on chunk bits 0-1).
// Staging: linear LDS dest; global SOURCE pre-swizzled with the same involution.

__device__ __forceinline__ bf16x8 lds_frag(const unsigned short* buf, int row, int s) {
  int c = (row << 2) | ((s ^ (row >> 1)) & 3);
  return *(const bf16x8*)(buf + (c << 3));
}

__device__ __forceinline__ void gemm_pipe(
    const unsigned short* __restrict__ A,   // [M][lda] bf16 row-major
    const unsigned short* __restrict__ Bt,  // [N][lda] bf16 row-major (B^T)
    int lda, int kt, int arow0, int brow0,
    unsigned short (*lA)[8192], unsigned short (*lB)[8192],
    f32x4 acc[8][4]) {
  const int tid = threadIdx.x;
  const int lane = tid & 63, w = tid >> 6;
  const int wrow = w >> 2, wcol = w & 3;   // 2 x 4 wave grid
  const int rl = lane & 15, s = lane >> 4;

  // staging: wave w covers chunks [w*128, w*128+128) of each 1024-chunk region
  int cA0 = w * 128 + lane;        int g0 = cA0 ^ ((cA0 >> 3) & 3);
  int cA1 = w * 128 + 64 + lane;   int g1 = cA1 ^ ((cA1 >> 3) & 3);
  const unsigned short* pA0 = A  + (size_t)(arow0 + (g0 >> 2)) * lda + (g0 & 3) * 8;
  const unsigned short* pA1 = A  + (size_t)(arow0 + (g1 >> 2)) * lda + (g1 & 3) * 8;
  const unsigned short* pB0 = Bt + (size_t)(brow0 + (g0 >> 2)) * lda + (g0 & 3) * 8;
  const unsigned short* pB1 = Bt + (size_t)(brow0 + (g1 >> 2)) * lda + (g1 & 3) * 8;
  const int lo0 = (w * 128) * 8;        // element offset of wave-uniform LDS base
  const int lo1 = (w * 128 + 64) * 8;

#define STAGE(t)                                                              \
  do { int _b = (t) & 3; size_t _k = (size_t)(t) * GBK;                       \
    GLOAD16(pA0 + _k, &lA[_b][lo0]);                                          \
    GLOAD16(pA1 + _k, &lA[_b][lo1]);                                          \
    GLOAD16(pB0 + _k, &lB[_b][lo0]);                                          \
    GLOAD16(pB1 + _k, &lB[_b][lo1]);                                          \
  } while (0)

  STAGE(0); STAGE(1); STAGE(2);   // 12 loads/thread in flight
  asm volatile("s_waitcnt vmcnt(8)" ::: "memory");   // tile 0 landed
  __builtin_amdgcn_s_barrier();
  __builtin_amdgcn_sched_barrier(0);

  for (int t = 0; t < kt; ++t) {
    if (t + 3 < kt) STAGE(t + 3);  // buffer freed at end of iter t-1
    const unsigned short* bufA = lA[t & 3];
    const unsigned short* bufB = lB[t & 3];
    bf16x8 bf[4], af[4];
#pragma unroll
    for (int n = 0; n < 4; n++) bf[n] = lds_frag(bufB, wcol * 64 + n * 16 + rl, s);
#pragma unroll
    for (int m = 0; m < 4; m++) af[m] = lds_frag(bufA, wrow * 128 + m * 16 + rl, s);
    __builtin_amdgcn_s_setprio(1);
#pragma unroll
    for (int m = 0; m < 4; m++)
#pragma unroll
      for (int n = 0; n < 4; n++)
        acc[m][n] = __builtin_amdgcn_mfma_f32_16x16x32_bf16(af[m], bf[n], acc[m][n], 0, 0, 0);
    __builtin_amdgcn_s_setprio(0);
#pragma unroll
    for (int m = 0; m < 4; m++) af[m] = lds_frag(bufA, wrow * 128 + 64 + m * 16 + rl, s);
    __builtin_amdgcn_s_setprio(1);
#pragma unroll
    for (int m = 0; m < 4; m++)
#pragma unroll
      for (int n = 0; n < 4; n++)
        acc[m + 4][n] = __builtin_amdgcn_mfma_f32_16x16x32_bf16(af[m], bf[n], acc[m + 4][n], 0, 0, 0);
    __builtin_amdgcn_s_setprio(0);
    if (t < kt - 1) {
      if (t + 3 < kt)      asm volatile("s_waitcnt vmcnt(8)" ::: "memory");
      else if (t + 2 < kt) asm volatile("s_waitcnt vmcnt(4)" ::: "memory");
      else                 asm volatile("s_waitcnt vmcnt(0)" ::: "memory");
      __builtin_amdgcn_s_barrier();
      __builtin_amdgcn_sched_barrier(0);
    }
  }
  // drain so caller may restage buffers (second segment) safely
  asm volatile("s_waitcnt vmcnt(0)" ::: "memory");
  __builtin_amdgcn_s_barrier();
  __builtin_amdgcn_sched_barrier(0);
#undef STAGE
}

// u = bf16( svec[col] * (xc @ W_in + b_in) )
__global__ __launch_bounds__(512, 2) void gemm_u_kernel(
    const unsigned short* __restrict__ xc, const unsigned short* __restrict__ Wtin,
    const float* __restrict__ b_in, const float* __restrict__ svec,
    unsigned short* __restrict__ u) {
  __shared__ __align__(16) unsigned short lA[4][8192];
  __shared__ __align__(16) unsigned short lB[4][8192];
  f32x4 acc[8][4];
  const f32x4 z = {0.f, 0.f, 0.f, 0.f};
#pragma unroll
  for (int i = 0; i < 8; i++)
#pragma unroll
    for (int n = 0; n < 4; n++) acc[i][n] = z;

  int bid = blockIdx.x;
  int swz = (bid & 7) * 64 + (bid >> 3);   // 512 % 8 == 0: bijective
  int bcol = swz >> 7, brow = swz & 127;

  gemm_pipe(xc, Wtin, KC, KC / GBK, brow * 256, bcol * 256, lA, lB, acc);

  const int lane = threadIdx.x & 63, w = threadIdx.x >> 6;
  const int wrow = w >> 2, wcol = w & 3;
  const int rl = lane & 15, s = lane >> 4;
  const int colb = bcol * 256 + wcol * 64 + rl;
  const int rowb = brow * 256 + wrow * 128 + s * 4;
#pragma unroll
  for (int n = 0; n < 4; n++) {
    int col = colb + n * 16;
    float bi = b_in[col], sv = svec[col];
#pragma unroll
    for (int i = 0; i < 8; i++) {
#pragma unroll
      for (int r = 0; r < 4; r++) {
        int row = rowb + i * 16 + r;
        u[(size_t)row * DHID + col] = f2bf((acc[i][n][r] + bi) * sv);
      }
    }
  }
}

// out = 0.5f * (xc @ W_dx + h @ W_out + b_dx + b_out)
__global__ __launch_bounds__(512, 2) void gemm_out_kernel(
    const unsigned short* __restrict__ xc, const unsigned short* __restrict__ Wtdx,
    const unsigned short* __restrict__ h, const unsigned short* __restrict__ Wtout,
    const float* __restrict__ b_dx, const float* __restrict__ b_out,
    float* __restrict__ out) {
  __shared__ __align__(16) unsigned short lA[4][8192];
  __shared__ __align__(16) unsigned short lB[4][8192];
  f32x4 acc[8][4];
  const f32x4 z = {0.f, 0.f, 0.f, 0.f};
#pragma unroll
  for (int i = 0; i < 8; i++)
#pragma unroll
    for (int n = 0; n < 4; n++) acc[i][n] = z;

  int bid = blockIdx.x;
  int swz = (bid & 7) * 64 + (bid >> 3);
  int bcol = swz >> 7, brow = swz & 127;

  gemm_pipe(xc, Wtdx, KC, KC / GBK, brow * 256, bcol * 256, lA, lB, acc);
  gemm_pipe(h, Wtout, DHID, DHID / GBK, brow * 256, bcol * 256, lA, lB, acc);

  const int lane = threadIdx.x & 63, w = threadIdx.x >> 6;
  const int wrow = w >> 2, wcol = w & 3;
  const int rl = lane & 15, s = lane >> 4;
  const int colb = bcol * 256 + wcol * 64 + rl;
  const int rowb = brow * 256 + wrow * 128 + s * 4;
#pragma unroll
  for (int n = 0; n < 4; n++) {
    int col = colb + n * 16;
    float bb = b_dx[col] + b_out[col];
#pragma unroll
    for (int i = 0; i < 8; i++) {
#pragma unroll
      for (int r = 0; r < 4; r++) {
        int row = rowb + i * 16 + r;
        out[(size_t)row * DOUT + col] = 0.5f * (acc[i][n][r] + bb);
      }
    }
  }
}

// ---------------- chunked scan: h_t = a h_{t-1} + u_t ----------------

__global__ __launch_bounds__(256) void scan1_kernel(
    const float* __restrict__ avec, unsigned short* __restrict__ uh,
    float* __restrict__ carry) {
  int blk = blockIdx.x;            // b(8) x c(32) x dblk(4)
  int d = (blk & 3) * 256 + threadIdx.x;
  int c = (blk >> 2) & 31;
  int b = blk >> 7;
  float a = avec[d];
  unsigned short* p = uh + ((size_t)(b * S_DIM + c * LCHUNK)) * DHID + d;
  float h = 0.f;
#pragma unroll 4
  for (int t = 0; t < LCHUNK; t++) {
    float uv = bf2f(p[(size_t)t * DHID]);
    h = fmaf(a, h, uv);
    p[(size_t)t * DHID] = f2bf(h);
  }
  carry[((size_t)b * NCHUNK + c) * DHID + d] = h;
}

__global__ __launch_bounds__(256) void scan2_kernel(
    const float* __restrict__ avec, const float* __restrict__ carry,
    float* __restrict__ Hprev) {
  int gid = blockIdx.x * 256 + threadIdx.x;  // 0..8191
  int b = gid >> 10, d = gid & 1023;
  float a = avec[d];
  float aL = a;
#pragma unroll
  for (int i = 0; i < 7; i++) aL *= aL;  // a^128
  float H = 0.f;
#pragma unroll
  for (int c = 0; c < NCHUNK; c++) {
    size_t idx = ((size_t)b * NCHUNK + c) * DHID + d;
    Hprev[idx] = H;
    H = aL * H + carry[idx];
  }
}

__global__ __launch_bounds__(256) void scan3_kernel(
    const float* __restrict__ avec, unsigned short* __restrict__ uh,
    const float* __restrict__ Hprev) {
  int blk = blockIdx.x;
  int d = (blk & 3) * 256 + threadIdx.x;
  int c = (blk >> 2) & 31;
  int b = blk >> 7;
  float Hp = Hprev[((size_t)b * NCHUNK + c) * DHID + d];
  if (Hp == 0.f) return;  // c==0 (and exact zeros): values unchanged
  float a = avec[d];
  float pw = a;
  unsigned short* p = uh + ((size_t)(b * S_DIM + c * LCHUNK)) * DHID + d;
#pragma unroll 4
  for (int t = 0; t < LCHUNK; t++) {
    float hv = bf2f(p[(size_t)t * DHID]) + pw * Hp;
    p[(size_t)t * DHID] = f2bf(hv);
    pw *= a;
  }
}

// ---------------- launch ----------------

extern "C" void kernel_launch(void* const* d_in, const int* in_sizes, int n_in,
                              void* d_out, int out_size, void* d_ws, size_t ws_size,
                              hipStream_t stream) {
  const float* x       = (const float*)d_in[0];
  const float* a_logit = (const float*)d_in[1];
  const float* W_dx    = (const float*)d_in[2];
  const float* b_dx    = (const float*)d_in[3];
  const float* W_in    = (const float*)d_in[4];
  const float* b_in    = (const float*)d_in[5];
  const float* W_out   = (const float*)d_in[6];
  const float* b_out   = (const float*)d_in[7];
  float* out = (float*)d_out;

  char* ws = (char*)d_ws;
  size_t off = 0;
  auto alloc = [&](size_t bytes) {
    void* p = ws + off;
    off += (bytes + 255) & ~(size_t)255;
    return p;
  };
  unsigned short* xc    = (unsigned short*)alloc((size_t)MTOT * KC * 2);
  unsigned short* Wtdx  = (unsigned short*)alloc((size_t)DOUT * KC * 2);
  unsigned short* Wtin  = (unsigned short*)alloc((size_t)DHID * KC * 2);
  unsigned short* Wtout = (unsigned short*)alloc((size_t)DOUT * DHID * 2);
  unsigned short* uh    = (unsigned short*)alloc((size_t)MTOT * DHID * 2);
  float* carry = (float*)alloc((size_t)B_DIM * NCHUNK * DHID * 4);
  float* Hprev = (float*)alloc((size_t)B_DIM * NCHUNK * DHID * 4);
  float* avec  = (float*)alloc(DHID * 4);
  float* svec  = (float*)alloc(DHID * 4);
  (void)ws_size; (void)in_sizes; (void)n_in; (void)out_size;

  prep_a_kernel<<<4, 256, 0, stream>>>(a_logit, avec, svec);
  transpose_cast_kernel<<<dim3(KC / 32, 32), 256, 0, stream>>>(W_dx, Wtdx, KCAT, KC);
  transpose_cast_kernel<<<dim3(KC / 32, 32), 256, 0, stream>>>(W_in, Wtin, KCAT, KC);
  transpose_cast_kernel<<<dim3(32, 32), 256, 0, stream>>>(W_out, Wtout, DHID, DHID);
  build_xc_kernel<<<(MTOT * (KC / 4) + 255) / 256, 256, 0, stream>>>(x, xc);

  gemm_u_kernel<<<512, 512, 0, stream>>>(xc, Wtin, b_in, svec, uh);

  scan1_kernel<<<B_DIM * NCHUNK * 4, 256, 0, stream>>>(avec, uh, carry);
  scan2_kernel<<<32, 256, 0, stream>>>(avec, carry, Hprev);
  scan3_kernel<<<B_DIM * NCHUNK * 4, 256, 0, stream>>>(avec, uh, Hprev);

  gemm_out_kernel<<<512, 512, 0, stream>>>(xc, Wtdx, uh, Wtout, b_dx, b_out, out);
}

// Round 3
// 339.611 us; speedup vs baseline: 1.2701x; 1.2241x over previous
//
#include <hip/hip_runtime.h>
#include <hip/hip_bf16.h>
#include <math.h>

#define B_DIM 8
#define S_DIM 4096
#define DIN   1024
#define DHID  1024
#define DOUT  1024
#define KCAT  1040          // d_in + pe
#define KC    1088          // padded to %64==0 (17 K-tiles of 64)
#define MTOT  (B_DIM*S_DIM) // 32768
#define NCHUNK 32
#define LCHUNK 128

typedef __attribute__((ext_vector_type(8))) short bf16x8;
typedef __attribute__((ext_vector_type(4))) float f32x4;
typedef __attribute__((ext_vector_type(4))) unsigned short u16x4;

__device__ __forceinline__ unsigned short f2bf(float f) {
  union { float f; unsigned u; } v; v.f = f;
  unsigned r = v.u + 0x7fffu + ((v.u >> 16) & 1u);
  return (unsigned short)(r >> 16);
}
__device__ __forceinline__ float bf2f(unsigned short h) {
  union { unsigned u; float f; } v; v.u = ((unsigned)h) << 16;
  return v.f;
}

// async global->LDS, 16B per lane; LDS dest = wave-uniform base + lane*16
#define GLOAD16(g, l)                                                         \
  __builtin_amdgcn_global_load_lds(                                           \
      (const __attribute__((address_space(1))) void*)(g),                     \
      (__attribute__((address_space(3))) void*)(l), 16, 0, 0)

#define BAR()   __builtin_amdgcn_s_barrier()
#define LGKM0() do { asm volatile("s_waitcnt lgkmcnt(0)" ::: "memory");       \
                     __builtin_amdgcn_sched_barrier(0); } while (0)

// ---------------- prep kernels ----------------

__global__ void prep_a_kernel(const float* __restrict__ logit,
                              float* __restrict__ avec, float* __restrict__ svec) {
  int d = blockIdx.x * 256 + threadIdx.x;
  if (d >= DHID) return;
  float a = 1.f / (1.f + expf(-logit[d]));
  avec[d] = a;
  svec[d] = sqrtf(fmaxf(0.f, 1.f - a * a));
}

// W[K][N] fp32 -> Wt[N][KCdst] bf16 (zero-pad k >= Ksrc)
__global__ __launch_bounds__(256) void transpose_cast_kernel(
    const float* __restrict__ W, unsigned short* __restrict__ Wt,
    int Ksrc, int KCdst) {
  __shared__ float tile[32][33];
  const int N = 1024;
  int kb = blockIdx.x * 32, nb = blockIdx.y * 32;
  int tx = threadIdx.x & 31, ty = threadIdx.x >> 5;  // ty 0..7
#pragma unroll
  for (int r = 0; r < 32; r += 8) {
    int k = kb + ty + r;
    tile[ty + r][tx] = (k < Ksrc) ? W[(size_t)k * N + nb + tx] : 0.f;
  }
  __syncthreads();
#pragma unroll
  for (int r = 0; r < 32; r += 8) {
    int n = nb + ty + r;
    Wt[(size_t)n * KCdst + kb + tx] = f2bf(tile[tx][ty + r]);
  }
}

// xc[row][0..1023]=x, [1024..1039]=PE(t), [1040..1087]=0   (bf16)
__global__ __launch_bounds__(256) void build_xc_kernel(
    const float* __restrict__ x, unsigned short* __restrict__ xc) {
  int gid = blockIdx.x * 256 + threadIdx.x;  // over MTOT * (KC/4)
  if (gid >= MTOT * (KC / 4)) return;
  int row = gid / (KC / 4);
  int g = gid - row * (KC / 4);
  int col0 = g * 4;
  u16x4 val;
  if (col0 < DIN) {
    const float4 xv = *(const float4*)(x + (size_t)row * DIN + col0);
    val.x = f2bf(xv.x); val.y = f2bf(xv.y); val.z = f2bf(xv.z); val.w = f2bf(xv.w);
  } else {
    int t = row & (S_DIM - 1);
#pragma unroll
    for (int e = 0; e < 4; e++) {
      int col = col0 + e;
      float v = 0.f;
      if (col < KCAT) {
        int j = col - DIN;
        int i = j >> 1;
        float div = expf(-(float)i * 1.1512925465f);  // 10000^(-i/8)
        float arg = (float)t * div;
        v = (j & 1) ? cosf(arg) : sinf(arg);
      }
      val[e] = f2bf(v);
    }
  }
  *(u16x4*)(xc + (size_t)row * KC + col0) = val;
}

// ------------- 256x256 8-phase GEMM (BK=64, half-tile dbuf, counted vmcnt) -------
// Half-tile = [128 rows][64 K] bf16 = 16KB, chunk = 16B: chunk c = row*8 + slot.
// Swizzle: phys_slot = slot ^ (row & 7)  (involution; ds_read 2-way conflict = free).
// Staging: linear LDS dest (global_load_lds); global SOURCE pre-swizzled.

__device__ __forceinline__ bf16x8 frag(const unsigned short* hb, int row, int slot) {
  int ph = slot ^ (row & 7);
  return *(const bf16x8*)(hb + (size_t)row * 64 + ph * 8);
}

__device__ __forceinline__ void gemm_pipe2(
    const unsigned short* __restrict__ A,   // [M][lda] bf16 row-major
    const unsigned short* __restrict__ Bt,  // [N][lda] bf16 row-major (B^T)
    int lda, int kt, int arow0, int brow0,
    unsigned short (*lA)[2][8192], unsigned short (*lB)[2][8192],
    f32x4 acc[8][4]) {
  const int tid = threadIdx.x;
  const int lane = tid & 63, w = tid >> 6;
  const int wrow = w >> 2, wcol = w & 3;   // 2M x 4N wave grid, per-wave 128x64
  const int rl = lane & 15, s = lane >> 4;

  // staging: thread covers chunks c1 (rows 0-63) and c2 (rows 64-127) of a half
  const int c1 = tid, c2 = tid + 512;
  const int r1 = c1 >> 3, sl1 = (c1 & 7) ^ (r1 & 7);
  const int r2 = c2 >> 3, sl2 = (c2 & 7) ^ (r2 & 7);
  const unsigned short* pA1 = A + (size_t)(arow0 + r1) * lda + sl1 * 8;
  const unsigned short* pA2 = A + (size_t)(arow0 + r2) * lda + sl2 * 8;
  const unsigned short* pB1 = Bt + (size_t)(brow0 + r1) * lda + sl1 * 8;
  const unsigned short* pB2 = Bt + (size_t)(brow0 + r2) * lda + sl2 * 8;
  const size_t hstep = (size_t)128 * lda;

#define STG_A(t, h) do { size_t _o = (size_t)(t) * 64 + (size_t)(h) * hstep;  \
    int _b = (t) & 1;                                                         \
    GLOAD16(pA1 + _o, &lA[_b][h][(size_t)c1 * 8]);                            \
    GLOAD16(pA2 + _o, &lA[_b][h][(size_t)c2 * 8]); } while (0)
#define STG_B(t, h) do { size_t _o = (size_t)(t) * 64 + (size_t)(h) * hstep;  \
    int _b = (t) & 1;                                                         \
    GLOAD16(pB1 + _o, &lB[_b][h][(size_t)c1 * 8]);                            \
    GLOAD16(pB2 + _o, &lB[_b][h][(size_t)c2 * 8]); } while (0)

#define MFMA_Q(MH, NH, BB)                                                    \
  __builtin_amdgcn_s_setprio(1);                                              \
  _Pragma("unroll") for (int mq = 0; mq < 4; mq++)                            \
    _Pragma("unroll") for (int nq = 0; nq < 2; nq++)                          \
      _Pragma("unroll") for (int kk = 0; kk < 2; kk++)                        \
        acc[(MH)*4 + mq][(NH)*2 + nq] =                                       \
            __builtin_amdgcn_mfma_f32_16x16x32_bf16(                          \
                a[mq][kk], BB[nq][kk], acc[(MH)*4 + mq][(NH)*2 + nq], 0, 0, 0);\
  __builtin_amdgcn_s_setprio(0);

  // prologue: stage tiles 0 and 1 (kt >= 2 always here)
  STG_B(0, 0); STG_B(0, 1); STG_A(0, 0); STG_A(0, 1);
  STG_B(1, 0); STG_B(1, 1); STG_A(1, 0); STG_A(1, 1);
  asm volatile("s_waitcnt vmcnt(8)" ::: "memory");   // tile 0 landed; tile 1 in flight
  BAR();

  const int br = (wcol & 1) * 64;
  for (int t = 0; t < kt; ++t) {
    const bool st = (t + 2) < kt;           // stage tile t+2 this iteration
    const unsigned short* Ac = &lA[t & 1][wrow][0];
    const unsigned short* Bc = &lB[t & 1][wcol >> 1][0];
    bf16x8 a[4][2], b0[2][2], b1[2][2];

    // ---- P0: read A(mh0) + B(nh0); MFMA quadrant (0,0) ----
#pragma unroll
    for (int mq = 0; mq < 4; mq++)
#pragma unroll
      for (int kk = 0; kk < 2; kk++)
        a[mq][kk] = frag(Ac, mq * 16 + rl, kk * 4 + s);
#pragma unroll
    for (int nq = 0; nq < 2; nq++)
#pragma unroll
      for (int kk = 0; kk < 2; kk++)
        b0[nq][kk] = frag(Bc, br + nq * 16 + rl, kk * 4 + s);
    BAR(); LGKM0();
    MFMA_Q(0, 0, b0);
    BAR();

    // ---- P1: read B(nh1); MFMA quadrant (0,1) ----
#pragma unroll
    for (int nq = 0; nq < 2; nq++)
#pragma unroll
      for (int kk = 0; kk < 2; kk++)
        b1[nq][kk] = frag(Bc, br + 32 + nq * 16 + rl, kk * 4 + s);
    BAR(); LGKM0();
    MFMA_Q(0, 1, b1);
    BAR();

    // ---- P2: read A(mh1); stage B halves of t+2 (B slots freed after P1) ----
#pragma unroll
    for (int mq = 0; mq < 4; mq++)
#pragma unroll
      for (int kk = 0; kk < 2; kk++)
        a[mq][kk] = frag(Ac, 64 + mq * 16 + rl, kk * 4 + s);
    if (st) { STG_B(t + 2, 0); STG_B(t + 2, 1); }
    BAR(); LGKM0();
    MFMA_Q(1, 1, b1);
    BAR();

    // ---- P3: stage A halves of t+2 (A slots freed after P2); MFMA (1,0) ----
    if (st) { STG_A(t + 2, 0); STG_A(t + 2, 1); }
    BAR();
    MFMA_Q(1, 0, b0);
    if (st) { asm volatile("s_waitcnt vmcnt(8)" ::: "memory"); }   // tile t+1 landed
    else    { asm volatile("s_waitcnt vmcnt(0)" ::: "memory"); }
    BAR();
  }
#undef STG_A
#undef STG_B
#undef MFMA_Q
}

// u = bf16( svec[col] * (xc @ W_in + b_in) )
__global__ __launch_bounds__(512, 2) void gemm_u_kernel(
    const unsigned short* __restrict__ xc, const unsigned short* __restrict__ Wtin,
    const float* __restrict__ b_in, const float* __restrict__ svec,
    unsigned short* __restrict__ u) {
  __shared__ __align__(16) unsigned short lA[2][2][8192];
  __shared__ __align__(16) unsigned short lB[2][2][8192];
  f32x4 acc[8][4];
  const f32x4 z = {0.f, 0.f, 0.f, 0.f};
#pragma unroll
  for (int i = 0; i < 8; i++)
#pragma unroll
    for (int n = 0; n < 4; n++) acc[i][n] = z;

  int bid = blockIdx.x;
  int swz = (bid & 7) * 64 + (bid >> 3);   // 512 % 8 == 0: bijective
  int bcol = swz >> 7, brow = swz & 127;

  gemm_pipe2(xc, Wtin, KC, KC / 64, brow * 256, bcol * 256, lA, lB, acc);

  const int lane = threadIdx.x & 63, w = threadIdx.x >> 6;
  const int wrow = w >> 2, wcol = w & 3;
  const int rl = lane & 15, s = lane >> 4;
  const int colb = bcol * 256 + wcol * 64 + rl;
  const int rowb = brow * 256 + wrow * 128 + s * 4;
#pragma unroll
  for (int n = 0; n < 4; n++) {
    int col = colb + n * 16;
    float bi = b_in[col], sv = svec[col];
#pragma unroll
    for (int i = 0; i < 8; i++) {
#pragma unroll
      for (int r = 0; r < 4; r++) {
        int row = rowb + i * 16 + r;
        u[(size_t)row * DHID + col] = f2bf((acc[i][n][r] + bi) * sv);
      }
    }
  }
}

// out = 0.5f * (xc @ W_dx + h @ W_out + b_dx + b_out)
__global__ __launch_bounds__(512, 2) void gemm_out_kernel(
    const unsigned short* __restrict__ xc, const unsigned short* __restrict__ Wtdx,
    const unsigned short* __restrict__ h, const unsigned short* __restrict__ Wtout,
    const float* __restrict__ b_dx, const float* __restrict__ b_out,
    float* __restrict__ out) {
  __shared__ __align__(16) unsigned short lA[2][2][8192];
  __shared__ __align__(16) unsigned short lB[2][2][8192];
  f32x4 acc[8][4];
  const f32x4 z = {0.f, 0.f, 0.f, 0.f};
#pragma unroll
  for (int i = 0; i < 8; i++)
#pragma unroll
    for (int n = 0; n < 4; n++) acc[i][n] = z;

  int bid = blockIdx.x;
  int swz = (bid & 7) * 64 + (bid >> 3);
  int bcol = swz >> 7, brow = swz & 127;

  gemm_pipe2(xc, Wtdx, KC, KC / 64, brow * 256, bcol * 256, lA, lB, acc);
  gemm_pipe2(h, Wtout, DHID, DHID / 64, brow * 256, bcol * 256, lA, lB, acc);

  const int lane = threadIdx.x & 63, w = threadIdx.x >> 6;
  const int wrow = w >> 2, wcol = w & 3;
  const int rl = lane & 15, s = lane >> 4;
  const int colb = bcol * 256 + wcol * 64 + rl;
  const int rowb = brow * 256 + wrow * 128 + s * 4;
#pragma unroll
  for (int n = 0; n < 4; n++) {
    int col = colb + n * 16;
    float bb = b_dx[col] + b_out[col];
#pragma unroll
    for (int i = 0; i < 8; i++) {
#pragma unroll
      for (int r = 0; r < 4; r++) {
        int row = rowb + i * 16 + r;
        out[(size_t)row * DOUT + col] = 0.5f * (acc[i][n][r] + bb);
      }
    }
  }
}

// ---------------- chunked scan: h_t = a h_{t-1} + u_t ----------------

// pass 1: local scan per chunk (in place u->h_local, bf16), emit chunk carry.
// 4 d's per thread, vectorized u16x4 loads/stores (G13).
__global__ __launch_bounds__(256) void scan1_kernel(
    const float* __restrict__ avec, unsigned short* __restrict__ uh,
    float* __restrict__ carry) {
  int b = blockIdx.x >> 5, c = blockIdx.x & 31;
  int d0 = threadIdx.x * 4;
  float4 a4 = *(const float4*)(avec + d0);
  unsigned short* p = uh + ((size_t)(b * S_DIM + c * LCHUNK)) * DHID + d0;
  float h0 = 0.f, h1 = 0.f, h2 = 0.f, h3 = 0.f;
#pragma unroll 4
  for (int t = 0; t < LCHUNK; t++) {
    u16x4 v = *(u16x4*)(p + (size_t)t * DHID);
    h0 = fmaf(a4.x, h0, bf2f(v.x));
    h1 = fmaf(a4.y, h1, bf2f(v.y));
    h2 = fmaf(a4.z, h2, bf2f(v.z));
    h3 = fmaf(a4.w, h3, bf2f(v.w));
    v.x = f2bf(h0); v.y = f2bf(h1); v.z = f2bf(h2); v.w = f2bf(h3);
    *(u16x4*)(p + (size_t)t * DHID) = v;
  }
  float4 cv = {h0, h1, h2, h3};
  *(float4*)(carry + ((size_t)b * NCHUNK + c) * DHID + d0) = cv;
}

// pass 2: sequential combine over chunks (8192 threads)
__global__ __launch_bounds__(256) void scan2_kernel(
    const float* __restrict__ avec, const float* __restrict__ carry,
    float* __restrict__ Hprev) {
  int gid = blockIdx.x * 256 + threadIdx.x;  // 0..8191
  int b = gid >> 10, d = gid & 1023;
  float a = avec[d];
  float aL = a;
#pragma unroll
  for (int i = 0; i < 7; i++) aL *= aL;  // a^128
  float H = 0.f;
#pragma unroll
  for (int c = 0; c < NCHUNK; c++) {
    size_t idx = ((size_t)b * NCHUNK + c) * DHID + d;
    Hprev[idx] = H;
    H = aL * H + carry[idx];
  }
}

// pass 3: h_t += a^{t+1} * Hprev[chunk]
__global__ __launch_bounds__(256) void scan3_kernel(
    const float* __restrict__ avec, unsigned short* __restrict__ uh,
    const float* __restrict__ Hprev) {
  int b = blockIdx.x >> 5, c = blockIdx.x & 31;
  int d0 = threadIdx.x * 4;
  float4 Hp = *(const float4*)(Hprev + ((size_t)b * NCHUNK + c) * DHID + d0);
  if (Hp.x == 0.f && Hp.y == 0.f && Hp.z == 0.f && Hp.w == 0.f) return;  // c==0
  float4 a4 = *(const float4*)(avec + d0);
  float p0 = a4.x * Hp.x, p1 = a4.y * Hp.y, p2 = a4.z * Hp.z, p3 = a4.w * Hp.w;
  unsigned short* p = uh + ((size_t)(b * S_DIM + c * LCHUNK)) * DHID + d0;
#pragma unroll 4
  for (int t = 0; t < LCHUNK; t++) {
    u16x4 v = *(u16x4*)(p + (size_t)t * DHID);
    v.x = f2bf(bf2f(v.x) + p0);
    v.y = f2bf(bf2f(v.y) + p1);
    v.z = f2bf(bf2f(v.z) + p2);
    v.w = f2bf(bf2f(v.w) + p3);
    *(u16x4*)(p + (size_t)t * DHID) = v;
    p0 *= a4.x; p1 *= a4.y; p2 *= a4.z; p3 *= a4.w;
  }
}

// ---------------- launch ----------------

extern "C" void kernel_launch(void* const* d_in, const int* in_sizes, int n_in,
                              void* d_out, int out_size, void* d_ws, size_t ws_size,
                              hipStream_t stream) {
  const float* x       = (const float*)d_in[0];
  const float* a_logit = (const float*)d_in[1];
  const float* W_dx    = (const float*)d_in[2];
  const float* b_dx    = (const float*)d_in[3];
  const float* W_in    = (const float*)d_in[4];
  const float* b_in    = (const float*)d_in[5];
  const float* W_out   = (const float*)d_in[6];
  const float* b_out   = (const float*)d_in[7];
  float* out = (float*)d_out;

  char* ws = (char*)d_ws;
  size_t off = 0;
  auto alloc = [&](size_t bytes) {
    void* p = ws + off;
    off += (bytes + 255) & ~(size_t)255;
    return p;
  };
  unsigned short* xc    = (unsigned short*)alloc((size_t)MTOT * KC * 2);
  unsigned short* Wtdx  = (unsigned short*)alloc((size_t)DOUT * KC * 2);
  unsigned short* Wtin  = (unsigned short*)alloc((size_t)DHID * KC * 2);
  unsigned short* Wtout = (unsigned short*)alloc((size_t)DOUT * DHID * 2);
  unsigned short* uh    = (unsigned short*)alloc((size_t)MTOT * DHID * 2);
  float* carry = (float*)alloc((size_t)B_DIM * NCHUNK * DHID * 4);
  float* Hprev = (float*)alloc((size_t)B_DIM * NCHUNK * DHID * 4);
  float* avec  = (float*)alloc(DHID * 4);
  float* svec  = (float*)alloc(DHID * 4);
  (void)ws_size; (void)in_sizes; (void)n_in; (void)out_size;

  prep_a_kernel<<<4, 256, 0, stream>>>(a_logit, avec, svec);
  transpose_cast_kernel<<<dim3(KC / 32, 32), 256, 0, stream>>>(W_dx, Wtdx, KCAT, KC);
  transpose_cast_kernel<<<dim3(KC / 32, 32), 256, 0, stream>>>(W_in, Wtin, KCAT, KC);
  transpose_cast_kernel<<<dim3(32, 32), 256, 0, stream>>>(W_out, Wtout, DHID, DHID);
  build_xc_kernel<<<(MTOT * (KC / 4) + 255) / 256, 256, 0, stream>>>(x, xc);

  gemm_u_kernel<<<512, 512, 0, stream>>>(xc, Wtin, b_in, svec, uh);

  scan1_kernel<<<B_DIM * NCHUNK, 256, 0, stream>>>(avec, uh, carry);
  scan2_kernel<<<32, 256, 0, stream>>>(avec, carry, Hprev);
  scan3_kernel<<<B_DIM * NCHUNK, 256, 0, stream>>>(avec, uh, Hprev);

  gemm_out_kernel<<<512, 512, 0, stream>>>(xc, Wtdx, uh, Wtout, b_dx, b_out, out);
}